// Round 9
// baseline (3259.497 us; speedup 1.0000x reference)
//
#include <hip/hip_runtime.h>
#include <stdint.h>

typedef unsigned long long u64;

#define NB   32
#define TST  384
#define IDM  64
#define HDM  128
#define NCLS 10
#define EPSF 1e-7f
#define LOG2E 1.44269504088896340736f

// LDS layout (float offsets)
#define O_SBUF 0      // 388 (385 used) cached s_buf[t']
#define O_DELT 388    // 32  deltas from all batches
#define O_MISC 420    // 32: [0]=s_h, [8..16)=wsp per wave
#define O_ACT  452    // 192: x_t(64) | h(128)   (byte 1808, 16B-aligned)
#define O_GEX  644    // 512: FC feature double-buffered 2x256 (parity t&1)
#define O_RED  1156   // 1024: gate exchange [0..512) before S2; attn partials (8x128) after
#define O_WFC  2180   // 10*264 = 2640 padded W_fc
#define O_BFC  4820   // 12
#define SMTOT  4832

__device__ __forceinline__ float sigm(float x) {
  return 1.0f / (1.0f + __builtin_amdgcn_exp2f(-LOG2E * x));
}
__device__ __forceinline__ float tanh_f(float x) {
  return 1.0f - 2.0f / (1.0f + __builtin_amdgcn_exp2f(2.0f * LOG2E * x));
}

// full-rate DPP add (VALU pipe)
template <int CTRL>
__device__ __forceinline__ float dppadd(float v) {
  int t = __builtin_amdgcn_update_dpp(0, __builtin_bit_cast(int, v), CTRL, 0xF, 0xF, true);
  return v + __builtin_bit_cast(float, t);
}
__device__ __forceinline__ float sum8(float v) {
  v = dppadd<0xB1>(v);   // quad_perm xor1
  v = dppadd<0x4E>(v);   // quad_perm xor2
  v = dppadd<0x141>(v);  // row_half_mirror (xor4)
  return v;
}
__device__ __forceinline__ float sum16(float v) {
  v = dppadd<0xB1>(v);
  v = dppadd<0x4E>(v);
  v = dppadd<0x141>(v);
  v = dppadd<0x140>(v);  // row_mirror (xor8)
  return v;
}
__device__ __forceinline__ float wave_sum(float v) {
  v = sum16(v);
  v += __shfl_xor(v, 16, 64);
  v += __shfl_xor(v, 32, 64);
  return v;
}

// System-scope (sc0 sc1) 8B mailbox ops: bypass L1/L2, meet at the memory-side
// Infinity Cache; no cache-invalidate side effects. Monolithic load+waitcnt
// (the round-8 split issue/wait hid an outstanding load from the compiler —
// it could copy the dest VGPRs before the wait; reverted to the proven form).
__device__ __forceinline__ void mail_store(u64* p, u64 v) {
  asm volatile("global_store_dwordx2 %0, %1, off sc0 sc1"
               :: "v"(p), "v"(v) : "memory");
}
__device__ __forceinline__ u64 mail_load(u64* p) {
  u64 v;
  asm volatile("global_load_dwordx2 %0, %1, off sc0 sc1\n\t"
               "s_waitcnt vmcnt(0)"
               : "=v"(v) : "v"(p) : "memory");
  return v;
}

__global__ __launch_bounds__(512, 2)
void sab_kernel(const float* __restrict__ x, const float* __restrict__ Wih,
                const float* __restrict__ Whh, const float* __restrict__ bihp,
                const float* __restrict__ bhhp, const float* __restrict__ wtp,
                const float* __restrict__ Wfcp, const float* __restrict__ bfcp,
                float* __restrict__ dout, u64* __restrict__ mail) {
  __shared__ __align__(16) float SM[SMTOT];

  const int tid  = threadIdx.x;
  const int lane = tid & 63;
  const int wvid = tid >> 6;
  const int b    = blockIdx.x;
  const int go   = tid >> 3;          // gate octet 0..63
  const int kc   = tid & 7;           // K-chunk 0..7 (24 cols each)

  float* hsout = dout + (size_t)NB * TST * NCLS;     // hs region == attention buf
  const float* myx = x + (size_t)b * TST * IDM;

  // ---- preload weight sub-block: rows 8*go..8*go+7, cols 24*kc..24*kc+23 ----
  float w[8][24];
  #pragma unroll
  for (int i = 0; i < 8; ++i) {
    const int g = 8 * go + i;
    #pragma unroll
    for (int j = 0; j < 24; ++j) {
      const int k = 24 * kc + j;
      const float* sp = (k < IDM) ? (Wih + g * IDM + k) : (Whh + g * HDM + (k - IDM));
      w[i][j] = *sp;
    }
  }
  const float bias = bihp[tid] + bhhp[tid];

  // wave-0 cell state: dims j0=2*lane, j1=2*lane+1
  float wt0a = 0.f, wt0b = 0.f, wt1a = 0.f, wt1b = 0.f;
  if (wvid == 0) {
    const float2 w0 = reinterpret_cast<const float2*>(wtp)[lane];
    const float2 w1 = reinterpret_cast<const float2*>(wtp + HDM)[lane];
    wt0a = w0.x; wt0b = w0.y; wt1a = w1.x; wt1b = w1.y;
  }
  float cst0 = 0.f, cst1 = 0.f, hc0 = 0.f, hc1 = 0.f;

  // top-5 of s_buf, maintained uniformly on wave 0; s_buf[0]=0 pre-inserted
  float t5a = 0.f, t5b = -3e38f, t5c = -3e38f, t5d = -3e38f, t5e = -3e38f;

  // ---- init LDS ----
  for (int idx = tid; idx < NCLS * 256; idx += 512) {
    const int c = idx >> 8, k = idx & 255;
    SM[O_WFC + c * 264 + k] = Wfcp[idx];
  }
  if (tid < NCLS) SM[O_BFC + tid] = bfcp[tid];
  if (tid < HDM) SM[O_ACT + 64 + tid] = 0.f;   // h0 = 0
  if (tid < IDM) SM[O_ACT + tid] = myx[tid];   // x_0
  if (tid == 0) {
    SM[O_SBUF] = 0.f;
    mail_store(&mail[b], 0ull);
    mail_store(&mail[NB + b], 0ull);
  }
  __syncthreads();

  for (int t = 0; t < TST; ++t) {
    const int r = t + 1;
    const bool big = (r > 5);
    const int par = t & 1;

    // ================= gates: g = [x|h] @ W^T + bias (all 8 waves) ============
    float acc[8] = {0,0,0,0,0,0,0,0};
    {
      const float4* a4 = reinterpret_cast<const float4*>(SM + O_ACT + kc * 24);
      #pragma unroll
      for (int m = 0; m < 6; ++m) {
        const float4 av = a4[m];
        #pragma unroll
        for (int i = 0; i < 8; ++i) {
          acc[i] = fmaf(av.x, w[i][4*m+0], acc[i]);
          acc[i] = fmaf(av.y, w[i][4*m+1], acc[i]);
          acc[i] = fmaf(av.z, w[i][4*m+2], acc[i]);
          acc[i] = fmaf(av.w, w[i][4*m+3], acc[i]);
        }
      }
    }
    #pragma unroll
    for (int i = 0; i < 8; ++i) acc[i] = sum8(acc[i]);   // octet butterfly (VALU)
    float pre = acc[0];
    #pragma unroll
    for (int i = 1; i < 8; ++i) if (kc == i) pre = acc[i];  // this thread's gate = tid
    pre += bias;
    const bool tg = (tid >= 256) && (tid < 384);            // gg gates -> tanh
    SM[O_RED + tid] = tg ? tanh_f(pre) : sigm(pre);
    __syncthreads();                                        // S1

    // ===== window: cell+publish (w0) | poll (w7) | FC t-1 (w2-4) | x (w6) =====
    if (wvid == 0) {
      const float2 gi  = *reinterpret_cast<const float2*>(SM + O_RED + 2 * lane);
      const float2 gf  = *reinterpret_cast<const float2*>(SM + O_RED + 128 + 2 * lane);
      const float2 gg  = *reinterpret_cast<const float2*>(SM + O_RED + 256 + 2 * lane);
      const float2 go2 = *reinterpret_cast<const float2*>(SM + O_RED + 384 + 2 * lane);
      cst0 = gf.x * cst0 + gi.x * gg.x;
      cst1 = gf.y * cst1 + gi.y * gg.y;
      hc0  = go2.x * tanh_f(cst0);
      hc1  = go2.y * tanh_f(cst1);
      const float sh = wave_sum(tanh_f(hc0) * wt0a + tanh_f(hc1) * wt0b);
      if (lane == 0) {
        SM[O_MISC] = sh;
        if (big) {
          const u64 pv = (((u64)(unsigned)r) << 32) | (u64)__float_as_uint(t5e + sh + EPSF);
          mail_store(&mail[(r & 1) * NB + b], pv);
        }
      }
    } else if (wvid == 7) {
      if (big && lane < NB) {
        u64* slot = &mail[(r & 1) * NB + lane];
        u64 v = mail_load(slot);
        while ((unsigned)(v >> 32) != (unsigned)r) v = mail_load(slot);
        SM[O_DELT + lane] = __uint_as_float((unsigned)v);
      }
    } else if (wvid == 6) {
      if (t + 1 < TST) SM[O_ACT + lane] = myx[(size_t)(t + 1) * IDM + lane];
    } else if (t > 0 && tid >= 128 && tid < 288) {   // waves 2-4: FC for step t-1
      const int cls = (tid - 128) >> 4, p = tid & 15;
      const int gb = O_GEX + ((t - 1) & 1) * 256;
      float pt = 0.f;
      #pragma unroll
      for (int i = 0; i < 16; ++i) {
        const int k = p + 16 * i;
        pt = fmaf(SM[O_WFC + cls * 264 + k], SM[gb + k], pt);
      }
      pt = sum16(pt);
      if (p == 0) dout[((size_t)(b * TST + (t - 1))) * NCLS + cls] = pt + SM[O_BFC + cls];
    }
    __syncthreads();                                        // S2

    // ========== attention: per-wave scores + ballot gather (no compaction) =====
    const float s_h = SM[O_MISC];
    const int tp = tid;                 // position index (512 >= 384 positions)
    float wval = 0.f;
    bool pred = false;
    if (big) {
      if (tp < r) {
        const float sc = s_h + SM[O_SBUF + tp];
        wval = fmaxf(sc - SM[O_DELT + ((b * r + tp) & (NB - 1))], 0.f);
        pred = (wval > 0.f) && (tp > 0);   // t'=0 row is zeros: no contribution
      }
    } else {
      float scv = (tp < r) ? (s_h + SM[O_SBUF + tp]) : -3e38f;
      float mx = scv;
      mx = fmaxf(mx, __shfl_xor(mx, 1, 64));  mx = fmaxf(mx, __shfl_xor(mx, 2, 64));
      mx = fmaxf(mx, __shfl_xor(mx, 4, 64));  mx = fmaxf(mx, __shfl_xor(mx, 8, 64));
      mx = fmaxf(mx, __shfl_xor(mx, 16, 64)); mx = fmaxf(mx, __shfl_xor(mx, 32, 64));
      if (tp < r) {
        wval = __builtin_amdgcn_exp2f(LOG2E * (scv - mx));
        pred = (tp > 0);
      }
    }
    const float wsp = wave_sum(wval);        // includes t'=0 weight (denominator)
    if (lane == 0) SM[O_MISC + 8 + wvid] = wsp;

    // gather this wave's nonzeros (unnormalized), 2 dims per lane
    float g0 = 0.f, g1 = 0.f;
    u64 m = __ballot((int)pred);
    while (m) {
      const int l = __builtin_ctzll(m); m &= m - 1;
      const float wgt = __shfl(wval, l, 64);
      const int row = (wvid << 6) + l - 1;     // buf[tp] == hs row tp-1
      const float2 v = reinterpret_cast<const float2*>(
          hsout + (size_t)(b * TST + row) * HDM)[lane];
      g0 = fmaf(wgt, v.x, g0);
      g1 = fmaf(wgt, v.y, g1);
    }
    reinterpret_cast<float2*>(SM + O_RED + wvid * 128)[lane] = make_float2(g0, g1);
    __syncthreads();                                        // S3

    // ================= finalize (wave 0): h, outputs, s_buf[r], top-5 ==========
    if (wvid == 0) {
      float wsum = 0.f;
      #pragma unroll
      for (int i = 0; i < 8; ++i) wsum += SM[O_MISC + 8 + i];
      const float inv = 1.0f / (wsum + (big ? EPSF : 0.0f));
      float a0 = 0.f, a1 = 0.f;
      #pragma unroll
      for (int wv2 = 0; wv2 < 8; ++wv2) {
        const float2 p2 = reinterpret_cast<const float2*>(SM + O_RED + wv2 * 128)[lane];
        a0 += p2.x; a1 += p2.y;
      }
      const float at0 = a0 * inv, at1 = a1 * inv;
      const float hf0 = hc0 + at0, hf1 = hc1 + at1;
      const float2 hv = make_float2(hf0, hf1);
      reinterpret_cast<float2*>(hsout + (size_t)(b * TST + t) * HDM)[lane] = hv;
      reinterpret_cast<float2*>(SM + O_ACT + 64)[lane] = hv;
      reinterpret_cast<float2*>(SM + O_GEX + par * 256)[lane] = hv;
      reinterpret_cast<float2*>(SM + O_GEX + par * 256 + 128)[lane] = make_float2(at0, at1);
      if (r < TST) {
        const float tb = wave_sum(tanh_f(hf0) * wt1a + tanh_f(hf1) * wt1b);
        if (lane == 0) SM[O_SBUF + r] = tb;
        if (tb > t5e) {                // uniform insert across wave 0
          if (tb > t5a)      { t5e=t5d; t5d=t5c; t5c=t5b; t5b=t5a; t5a=tb; }
          else if (tb > t5b) { t5e=t5d; t5d=t5c; t5c=t5b; t5b=tb; }
          else if (tb > t5c) { t5e=t5d; t5d=t5c; t5c=tb; }
          else if (tb > t5d) { t5e=t5d; t5d=tb; }
          else               { t5e=tb; }
        }
      }
    }
    __syncthreads();                                        // S4 (loop end)
  }

  // final FC for t = 383 (parity (TST-1)&1)
  if (tid < 160) {
    const int cls = tid >> 4, p = tid & 15;
    const int gb = O_GEX + ((TST - 1) & 1) * 256;
    float pt = 0.f;
    #pragma unroll
    for (int i = 0; i < 16; ++i) {
      const int k = p + 16 * i;
      pt = fmaf(SM[O_WFC + cls * 264 + k], SM[gb + k], pt);
    }
    pt = sum16(pt);
    if (p == 0) dout[((size_t)(b * TST + (TST - 1))) * NCLS + cls] = pt + SM[O_BFC + cls];
  }
}

extern "C" void kernel_launch(void* const* d_in, const int* in_sizes, int n_in,
                              void* d_out, int out_size, void* d_ws, size_t ws_size,
                              hipStream_t stream) {
  const float* x   = (const float*)d_in[0];
  const float* Wih = (const float*)d_in[1];
  const float* Whh = (const float*)d_in[2];
  const float* bih = (const float*)d_in[3];
  const float* bhh = (const float*)d_in[4];
  const float* wt  = (const float*)d_in[5];
  const float* Wfc = (const float*)d_in[6];
  const float* bfc = (const float*)d_in[7];
  sab_kernel<<<dim3(NB), dim3(512), 0, stream>>>(
      x, Wih, Whh, bih, bhh, wt, Wfc, bfc, (float*)d_out, (u64*)d_ws);
}

// Round 10
// 2546.406 us; speedup vs baseline: 1.2800x; 1.2800x over previous
//
#include <hip/hip_runtime.h>
#include <stdint.h>

typedef unsigned long long u64;

#define NB   32
#define TST  384
#define IDM  64
#define HDM  128
#define NCLS 10
#define EPSF 1e-7f
#define LOG2E 1.44269504088896340736f

// LDS layout (float offsets)
#define O_SBUF 0      // 388 (385 used) cached s_buf[t']
#define O_WLDS 388    // 388 attention weights w[t']
#define O_DELT 776    // 32  deltas from all batches
#define O_MISC 808    // 32: [0]=s_h, [8..24)=wsp per wave, [24..29)=top5
#define O_ACT  840    // 192: x_t(64) | h(128)        (byte 3360, 16B-aligned)
#define O_GEX  1032   // 512: FC feature 2x256 (parity t&1)
#define O_GEXC 1544   // 512: gate exchange            (byte 6176, 16B-aligned)
#define O_RED  2056   // 768: attn partials 6 regions x 128 (byte 8224, 16B-aligned)
#define O_IDX  2824   // 384 ints: per-wave-region compacted positions (64/wave, waves 0..5)
#define O_WFC  3208   // 10*264 = 2640 padded W_fc
#define O_BFC  5848   // 12
#define SMTOT  5860

__device__ __forceinline__ float sigm(float x) {
  return 1.0f / (1.0f + __builtin_amdgcn_exp2f(-LOG2E * x));
}
__device__ __forceinline__ float tanh_f(float x) {
  return 1.0f - 2.0f / (1.0f + __builtin_amdgcn_exp2f(2.0f * LOG2E * x));
}

// full-rate DPP add (VALU pipe)
template <int CTRL>
__device__ __forceinline__ float dppadd(float v) {
  int t = __builtin_amdgcn_update_dpp(0, __builtin_bit_cast(int, v), CTRL, 0xF, 0xF, true);
  return v + __builtin_bit_cast(float, t);
}
__device__ __forceinline__ float sum8(float v) {
  v = dppadd<0xB1>(v);   // quad_perm xor1
  v = dppadd<0x4E>(v);   // quad_perm xor2
  v = dppadd<0x141>(v);  // row_half_mirror (xor4)
  return v;
}
__device__ __forceinline__ float sum16(float v) {
  v = dppadd<0xB1>(v);
  v = dppadd<0x4E>(v);
  v = dppadd<0x141>(v);
  v = dppadd<0x140>(v);  // row_mirror (xor8)
  return v;
}
__device__ __forceinline__ float wave_sum(float v) {
  v = sum16(v);
  v += __shfl_xor(v, 16, 64);
  v += __shfl_xor(v, 32, 64);
  return v;
}

// System-scope (sc0 sc1) 8B mailbox ops: bypass L1/L2, meet at the memory-side
// Infinity Cache; no cache-invalidate side effects. Monolithic load+waitcnt.
__device__ __forceinline__ void mail_store(u64* p, u64 v) {
  asm volatile("global_store_dwordx2 %0, %1, off sc0 sc1"
               :: "v"(p), "v"(v) : "memory");
}
__device__ __forceinline__ u64 mail_load(u64* p) {
  u64 v;
  asm volatile("global_load_dwordx2 %0, %1, off sc0 sc1\n\t"
               "s_waitcnt vmcnt(0)"
               : "=v"(v) : "v"(p) : "memory");
  return v;
}

__global__ __launch_bounds__(1024, 4)
void sab_kernel(const float* __restrict__ x, const float* __restrict__ Wih,
                const float* __restrict__ Whh, const float* __restrict__ bihp,
                const float* __restrict__ bhhp, const float* __restrict__ wtp,
                const float* __restrict__ Wfcp, const float* __restrict__ bfcp,
                float* __restrict__ dout, u64* __restrict__ mail) {
  __shared__ __align__(16) float SM[SMTOT];
  int* IDX = (int*)(SM + O_IDX);

  const int tid  = threadIdx.x;
  const int lane = tid & 63;
  const int wvid = tid >> 6;          // 0..15
  const int b    = blockIdx.x;
  const int gq   = tid >> 3;          // 4-gate group 0..127
  const int kc   = tid & 7;           // K-chunk 0..7 (24 cols each)

  float* hsout = dout + (size_t)NB * TST * NCLS;     // hs region == attention buf
  const float* myx = x + (size_t)b * TST * IDM;

  // ---- register-resident weights: 4 gates x 24 K-cols = 96 VGPRs ----
  float w[4][24];
  #pragma unroll
  for (int i = 0; i < 4; ++i) {
    const int g = 4 * gq + i;
    #pragma unroll
    for (int j = 0; j < 24; ++j) {
      const int k = 24 * kc + j;
      w[i][j] = (k < IDM) ? Wih[g * IDM + k] : Whh[g * HDM + (k - IDM)];
    }
  }
  const int myg = 4 * gq + kc;                       // valid when kc<4
  const float biasv = (kc < 4) ? (bihp[myg] + bhhp[myg]) : 0.f;
  const bool tg = (kc < 4) && (myg >= 256) && (myg < 384);   // gg gates -> tanh

  // wave-0 cell state: dims 2*lane, 2*lane+1
  float wt0a = 0.f, wt0b = 0.f, wt1a = 0.f, wt1b = 0.f;
  if (wvid == 0) {
    const float2 w0 = reinterpret_cast<const float2*>(wtp)[lane];
    const float2 w1 = reinterpret_cast<const float2*>(wtp + HDM)[lane];
    wt0a = w0.x; wt0b = w0.y; wt1a = w1.x; wt1b = w1.y;
  }
  float cst0 = 0.f, cst1 = 0.f, hc0 = 0.f, hc1 = 0.f;

  // ---- init LDS ----
  for (int idx = tid; idx < NCLS * 256; idx += 1024) {
    SM[O_WFC + (idx >> 8) * 264 + (idx & 255)] = Wfcp[idx];
  }
  if (tid < NCLS) SM[O_BFC + tid] = bfcp[tid];
  if (tid < HDM) SM[O_ACT + 64 + tid] = 0.f;   // h0 = 0
  if (tid < IDM) SM[O_ACT + tid] = myx[tid];   // x_0
  if (tid == 0) {
    SM[O_SBUF] = 0.f;
    SM[O_MISC + 24] = 0.f;        // top5: s_buf[0]=0 pre-inserted
    SM[O_MISC + 25] = -3e38f; SM[O_MISC + 26] = -3e38f;
    SM[O_MISC + 27] = -3e38f; SM[O_MISC + 28] = -3e38f;
    mail_store(&mail[b], 0ull);
    mail_store(&mail[NB + b], 0ull);
  }
  __syncthreads();

  for (int t = 0; t < TST; ++t) {
    const int r = t + 1;
    const bool big = (r > 5);
    const int par = t & 1;

    // ================= gates: g = [x|h] @ W^T + bias (register weights) ========
    float a0 = 0.f, a1 = 0.f, a2 = 0.f, a3 = 0.f;
    {
      const float4* a4 = reinterpret_cast<const float4*>(SM + O_ACT + kc * 24);
      #pragma unroll
      for (int m = 0; m < 6; ++m) {
        const float4 av = a4[m];
        a0 = fmaf(av.x, w[0][4*m+0], a0); a0 = fmaf(av.y, w[0][4*m+1], a0);
        a0 = fmaf(av.z, w[0][4*m+2], a0); a0 = fmaf(av.w, w[0][4*m+3], a0);
        a1 = fmaf(av.x, w[1][4*m+0], a1); a1 = fmaf(av.y, w[1][4*m+1], a1);
        a1 = fmaf(av.z, w[1][4*m+2], a1); a1 = fmaf(av.w, w[1][4*m+3], a1);
        a2 = fmaf(av.x, w[2][4*m+0], a2); a2 = fmaf(av.y, w[2][4*m+1], a2);
        a2 = fmaf(av.z, w[2][4*m+2], a2); a2 = fmaf(av.w, w[2][4*m+3], a2);
        a3 = fmaf(av.x, w[3][4*m+0], a3); a3 = fmaf(av.y, w[3][4*m+1], a3);
        a3 = fmaf(av.z, w[3][4*m+2], a3); a3 = fmaf(av.w, w[3][4*m+3], a3);
      }
    }
    a0 = sum8(a0); a1 = sum8(a1); a2 = sum8(a2); a3 = sum8(a3);
    float pre = a0;
    if (kc == 1) pre = a1;
    if (kc == 2) pre = a2;
    if (kc == 3) pre = a3;
    pre += biasv;
    if (kc < 4) SM[O_GEXC + myg] = tg ? tanh_f(pre) : sigm(pre);
    __syncthreads();                                        // B1

    // ===== window: cell+publish (w0) | poll (w15) | x (w14) | FC t-1 (w2-4) ====
    if (wvid == 0) {
      const float2 gi  = *reinterpret_cast<const float2*>(SM + O_GEXC + 2 * lane);
      const float2 gf  = *reinterpret_cast<const float2*>(SM + O_GEXC + 128 + 2 * lane);
      const float2 gg2 = *reinterpret_cast<const float2*>(SM + O_GEXC + 256 + 2 * lane);
      const float2 go2 = *reinterpret_cast<const float2*>(SM + O_GEXC + 384 + 2 * lane);
      cst0 = gf.x * cst0 + gi.x * gg2.x;
      cst1 = gf.y * cst1 + gi.y * gg2.y;
      hc0  = go2.x * tanh_f(cst0);
      hc1  = go2.y * tanh_f(cst1);
      const float sh = wave_sum(tanh_f(hc0) * wt0a + tanh_f(hc1) * wt0b);
      if (lane == 0) {
        SM[O_MISC] = sh;
        if (big) {
          const float t5e = SM[O_MISC + 28];
          const u64 pv = (((u64)(unsigned)r) << 32) | (u64)__float_as_uint(t5e + sh + EPSF);
          mail_store(&mail[(r & 1) * NB + b], pv);
        }
      }
    } else if (wvid == 15) {
      if (big && lane < NB) {
        u64* slot = &mail[(r & 1) * NB + lane];
        u64 v = mail_load(slot);
        while ((unsigned)(v >> 32) != (unsigned)r) v = mail_load(slot);
        SM[O_DELT + lane] = __uint_as_float((unsigned)v);
      }
    } else if (wvid == 14) {
      if (t + 1 < TST && lane < IDM)
        SM[O_ACT + lane] = myx[(size_t)(t + 1) * IDM + lane];
    } else if (t > 0 && tid >= 128 && tid < 288) {   // waves 2-4: FC for step t-1
      const int cls = (tid - 128) >> 4, p = tid & 15;
      const int gb = O_GEX + ((t - 1) & 1) * 256;
      float pt = 0.f;
      #pragma unroll
      for (int i = 0; i < 16; ++i) {
        const int k = p + 16 * i;
        pt = fmaf(SM[O_WFC + cls * 264 + k], SM[gb + k], pt);
      }
      pt = sum16(pt);
      if (p == 0) dout[((size_t)(b * TST + (t - 1))) * NCLS + cls] = pt + SM[O_BFC + cls];
    }
    __syncthreads();                                        // B2

    // ====== scores + own-wave compaction + distributed gather (no extra barrier) =====
    const float s_h = SM[O_MISC];
    float wval = 0.f;
    bool pred = false;
    if (big) {
      if (tid < r) {
        const float sc = s_h + SM[O_SBUF + tid];
        wval = fmaxf(sc - SM[O_DELT + ((b * r + tid) & (NB - 1))], 0.f);
        SM[O_WLDS + tid] = wval;
        pred = (wval > 0.f) && (tid > 0);
      }
    } else {
      float scv = (tid < r) ? (s_h + SM[O_SBUF + tid]) : -3e38f;
      float mx = scv;
      mx = fmaxf(mx, __shfl_xor(mx, 1, 64));  mx = fmaxf(mx, __shfl_xor(mx, 2, 64));
      mx = fmaxf(mx, __shfl_xor(mx, 4, 64));  mx = fmaxf(mx, __shfl_xor(mx, 8, 64));
      mx = fmaxf(mx, __shfl_xor(mx, 16, 64)); mx = fmaxf(mx, __shfl_xor(mx, 32, 64));
      if (tid < r) {
        wval = __builtin_amdgcn_exp2f(LOG2E * (scv - mx));
        SM[O_WLDS + tid] = wval;
        pred = (tid > 0);
      }
    }
    const float wsp = wave_sum(wval);        // per-wave denominator partial
    if (lane == 0) SM[O_MISC + 8 + wvid] = wsp;
    const u64 bmask = __ballot((int)pred);
    const int cnt = (int)__popcll(bmask);    // own-wave count, in-register
    if (pred) {
      const int pos = (int)__popcll(bmask & ((1ull << lane) - 1ull));
      IDX[(wvid << 6) + pos] = tid;          // pred => tid<r<=384 => wvid<6
    }
    // gather: 4 q-groups per wave take ranks (lane>>4)+4k of OWN wave's region;
    // 16 lanes x 8 dims each (proven distributed-latency pattern from R1/R6/R7)
    {
      const int sub = lane >> 4;             // 0..3
      const int j8 = tid & 15;
      float ac0=0.f,ac1=0.f,ac2=0.f,ac3=0.f,ac4=0.f,ac5=0.f,ac6=0.f,ac7=0.f;
      for (int rk = sub; rk < cnt; rk += 4) {
        const int tp = IDX[(wvid << 6) + rk];
        const float wgt = SM[O_WLDS + tp];
        const float* bp = hsout + ((size_t)(b * TST + tp - 1)) * HDM + j8 * 8;
        const float4 v0 = *reinterpret_cast<const float4*>(bp);
        const float4 v1 = *reinterpret_cast<const float4*>(bp + 4);
        ac0 = fmaf(wgt, v0.x, ac0); ac1 = fmaf(wgt, v0.y, ac1);
        ac2 = fmaf(wgt, v0.z, ac2); ac3 = fmaf(wgt, v0.w, ac3);
        ac4 = fmaf(wgt, v1.x, ac4); ac5 = fmaf(wgt, v1.y, ac5);
        ac6 = fmaf(wgt, v1.z, ac6); ac7 = fmaf(wgt, v1.w, ac7);
      }
      ac0 += __shfl_xor(ac0,16,64); ac0 += __shfl_xor(ac0,32,64);
      ac1 += __shfl_xor(ac1,16,64); ac1 += __shfl_xor(ac1,32,64);
      ac2 += __shfl_xor(ac2,16,64); ac2 += __shfl_xor(ac2,32,64);
      ac3 += __shfl_xor(ac3,16,64); ac3 += __shfl_xor(ac3,32,64);
      ac4 += __shfl_xor(ac4,16,64); ac4 += __shfl_xor(ac4,32,64);
      ac5 += __shfl_xor(ac5,16,64); ac5 += __shfl_xor(ac5,32,64);
      ac6 += __shfl_xor(ac6,16,64); ac6 += __shfl_xor(ac6,32,64);
      ac7 += __shfl_xor(ac7,16,64); ac7 += __shfl_xor(ac7,32,64);
      if (sub == 0 && wvid < 6) {
        float4* r4 = reinterpret_cast<float4*>(SM + O_RED + wvid * 128 + j8 * 8);
        r4[0] = make_float4(ac0, ac1, ac2, ac3);
        r4[1] = make_float4(ac4, ac5, ac6, ac7);
      }
    }
    __syncthreads();                                        // B3

    // ================= finalize (wave 0): h, outputs, s_buf[r], top-5 ==========
    if (wvid == 0) {
      float wsum = 0.f;
      #pragma unroll
      for (int i = 0; i < 16; ++i) wsum += SM[O_MISC + 8 + i];
      const float inv = 1.0f / (wsum + (big ? EPSF : 0.0f));
      float s0 = 0.f, s1 = 0.f;
      #pragma unroll
      for (int wv2 = 0; wv2 < 6; ++wv2) {
        const float2 p2 = reinterpret_cast<const float2*>(SM + O_RED + wv2 * 128)[lane];
        s0 += p2.x; s1 += p2.y;
      }
      const float at0 = s0 * inv, at1 = s1 * inv;
      const float hf0 = hc0 + at0, hf1 = hc1 + at1;
      const float2 hv = make_float2(hf0, hf1);
      reinterpret_cast<float2*>(hsout + (size_t)(b * TST + t) * HDM)[lane] = hv;
      reinterpret_cast<float2*>(SM + O_ACT + 64)[lane] = hv;
      reinterpret_cast<float2*>(SM + O_GEX + par * 256)[lane] = hv;
      reinterpret_cast<float2*>(SM + O_GEX + par * 256 + 128)[lane] = make_float2(at0, at1);
      if (r < TST) {
        const float tb = wave_sum(tanh_f(hf0) * wt1a + tanh_f(hf1) * wt1b);
        if (lane == 0) {
          SM[O_SBUF + r] = tb;
          float t5a = SM[O_MISC + 24], t5b = SM[O_MISC + 25], t5c = SM[O_MISC + 26];
          float t5d = SM[O_MISC + 27], t5e = SM[O_MISC + 28];
          if (tb > t5e) {
            if (tb > t5a)      { t5e=t5d; t5d=t5c; t5c=t5b; t5b=t5a; t5a=tb; }
            else if (tb > t5b) { t5e=t5d; t5d=t5c; t5c=t5b; t5b=tb; }
            else if (tb > t5c) { t5e=t5d; t5d=t5c; t5c=tb; }
            else if (tb > t5d) { t5e=t5d; t5d=tb; }
            else               { t5e=tb; }
            SM[O_MISC + 24] = t5a; SM[O_MISC + 25] = t5b; SM[O_MISC + 26] = t5c;
            SM[O_MISC + 27] = t5d; SM[O_MISC + 28] = t5e;
          }
        }
      }
    }
    __syncthreads();                                        // B4 (loop end)
  }

  // final FC for t = 383 (parity (TST-1)&1)
  if (tid < 160) {
    const int cls = tid >> 4, p = tid & 15;
    const int gb = O_GEX + ((TST - 1) & 1) * 256;
    float pt = 0.f;
    #pragma unroll
    for (int i = 0; i < 16; ++i) {
      const int k = p + 16 * i;
      pt = fmaf(SM[O_WFC + cls * 264 + k], SM[gb + k], pt);
    }
    pt = sum16(pt);
    if (p == 0) dout[((size_t)(b * TST + (TST - 1))) * NCLS + cls] = pt + SM[O_BFC + cls];
  }
}

extern "C" void kernel_launch(void* const* d_in, const int* in_sizes, int n_in,
                              void* d_out, int out_size, void* d_ws, size_t ws_size,
                              hipStream_t stream) {
  const float* x   = (const float*)d_in[0];
  const float* Wih = (const float*)d_in[1];
  const float* Whh = (const float*)d_in[2];
  const float* bih = (const float*)d_in[3];
  const float* bhh = (const float*)d_in[4];
  const float* wt  = (const float*)d_in[5];
  const float* Wfc = (const float*)d_in[6];
  const float* bfc = (const float*)d_in[7];
  sab_kernel<<<dim3(NB), dim3(1024), 0, stream>>>(
      x, Wih, Whh, bih, bhh, wt, Wfc, bfc, (float*)d_out, (u64*)d_ws);
}

// Round 11
// 1929.453 us; speedup vs baseline: 1.6893x; 1.3198x over previous
//
#include <hip/hip_runtime.h>
#include <stdint.h>

typedef unsigned long long u64;

#define NB   32
#define TST  384
#define IDM  64
#define HDM  128
#define NCLS 10
#define EPSF 1e-7f
#define LOG2E 1.44269504088896340736f

// LDS layout (float offsets)
#define O_SBUF 0      // 388 (385 used) cached s_buf[t']
#define O_WLDS 388    // 388 attention weights w[t']
#define O_DELT 776    // 32  deltas from all batches
#define O_MISC 808    // 32: [0]=s_h, [8..16)=wsp per wave
#define O_ACT  840    // 192: x_t(64) | h(128)      (byte 3360, 16B-aligned)
#define O_GEX  1032   // 256: FC feature [h | attn] (byte 4128, 16B-aligned)
#define O_RED  1288   // 1024: gates [0..512) during window; gather partials 6x128 after
#define O_IDX  2312   // 384 ints: per-wave compacted positions (64/wave, waves 0..5)
#define O_WFC  2696   // 10*264 = 2640 padded W_fc
#define O_BFC  5336   // 12
#define SMTOT  5348

__device__ __forceinline__ float sigm(float x) {
  return 1.0f / (1.0f + __builtin_amdgcn_exp2f(-LOG2E * x));
}
__device__ __forceinline__ float tanh_f(float x) {
  return 1.0f - 2.0f / (1.0f + __builtin_amdgcn_exp2f(2.0f * LOG2E * x));
}

// full-rate DPP add (VALU pipe)
template <int CTRL>
__device__ __forceinline__ float dppadd(float v) {
  int t = __builtin_amdgcn_update_dpp(0, __builtin_bit_cast(int, v), CTRL, 0xF, 0xF, true);
  return v + __builtin_bit_cast(float, t);
}
__device__ __forceinline__ float sum8(float v) {
  v = dppadd<0xB1>(v);   // quad_perm xor1
  v = dppadd<0x4E>(v);   // quad_perm xor2
  v = dppadd<0x141>(v);  // row_half_mirror (xor4)
  return v;
}
__device__ __forceinline__ float sum16(float v) {
  v = dppadd<0xB1>(v);
  v = dppadd<0x4E>(v);
  v = dppadd<0x141>(v);
  v = dppadd<0x140>(v);  // row_mirror (xor8)
  return v;
}
__device__ __forceinline__ float wave_sum(float v) {
  v = sum16(v);
  v += __shfl_xor(v, 16, 64);
  v += __shfl_xor(v, 32, 64);
  return v;
}

// System-scope (sc0 sc1) 8B mailbox ops: bypass L1/L2, meet at the memory-side
// Infinity Cache; no cache-invalidate side effects. Monolithic load+waitcnt
// (split issue/wait hid an in-flight load from the compiler — R8 failure).
__device__ __forceinline__ void mail_store(u64* p, u64 v) {
  asm volatile("global_store_dwordx2 %0, %1, off sc0 sc1"
               :: "v"(p), "v"(v) : "memory");
}
__device__ __forceinline__ u64 mail_load(u64* p) {
  u64 v;
  asm volatile("global_load_dwordx2 %0, %1, off sc0 sc1\n\t"
               "s_waitcnt vmcnt(0)"
               : "=v"(v) : "v"(p) : "memory");
  return v;
}

__global__ __launch_bounds__(512, 2)
void sab_kernel(const float* __restrict__ x, const float* __restrict__ Wih,
                const float* __restrict__ Whh, const float* __restrict__ bihp,
                const float* __restrict__ bhhp, const float* __restrict__ wtp,
                const float* __restrict__ Wfcp, const float* __restrict__ bfcp,
                float* __restrict__ dout, u64* __restrict__ mail) {
  __shared__ __align__(16) float SM[SMTOT];
  int* IDX = (int*)(SM + O_IDX);

  const int tid  = threadIdx.x;
  const int lane = tid & 63;
  const int wvid = tid >> 6;
  const int b    = blockIdx.x;
  const int go   = tid >> 3;          // gate octet 0..63
  const int kc   = tid & 7;           // K-chunk 0..7 (24 cols each)

  float* hsout = dout + (size_t)NB * TST * NCLS;     // hs region == attention buf
  const float* myx = x + (size_t)b * TST * IDM;

  // ---- weight sub-block: rows 8*go..8*go+7, cols 24*kc..24*kc+23 ----
  float w[8][24];
  #pragma unroll
  for (int i = 0; i < 8; ++i) {
    const int g = 8 * go + i;
    #pragma unroll
    for (int j = 0; j < 24; ++j) {
      const int k = 24 * kc + j;
      w[i][j] = (k < IDM) ? Wih[g * IDM + k] : Whh[g * HDM + (k - IDM)];
    }
  }
  const float bias = bihp[tid] + bhhp[tid];

  // wave-0 cell state: dims 2*lane, 2*lane+1
  float wt0a = 0.f, wt0b = 0.f, wt1a = 0.f, wt1b = 0.f;
  if (wvid == 0) {
    const float2 w0 = reinterpret_cast<const float2*>(wtp)[lane];
    const float2 w1 = reinterpret_cast<const float2*>(wtp + HDM)[lane];
    wt0a = w0.x; wt0b = w0.y; wt1a = w1.x; wt1b = w1.y;
  }
  float cst0 = 0.f, cst1 = 0.f, hc0 = 0.f, hc1 = 0.f;

  // top-5 of s_buf, uniform across wave 0; s_buf[0]=0 pre-inserted
  float t5a = 0.f, t5b = -3e38f, t5c = -3e38f, t5d = -3e38f, t5e = -3e38f;

  // ---- init LDS ----
  for (int idx = tid; idx < NCLS * 256; idx += 512)
    SM[O_WFC + (idx >> 8) * 264 + (idx & 255)] = Wfcp[idx];
  if (tid < NCLS) SM[O_BFC + tid] = bfcp[tid];
  if (tid < HDM) SM[O_ACT + 64 + tid] = 0.f;   // h0 = 0
  if (tid < IDM) SM[O_ACT + tid] = myx[tid];   // x_0
  if (tid == 0) {
    SM[O_SBUF] = 0.f;
    mail_store(&mail[b], 0ull);
    mail_store(&mail[NB + b], 0ull);
  }
  __syncthreads();

  for (int t = 0; t < TST; ++t) {
    const int r = t + 1;
    const bool big = (r > 5);

    // ================= gates: g = [x|h] @ W^T + bias =================
    float acc[8] = {0,0,0,0,0,0,0,0};
    {
      const float4* a4 = reinterpret_cast<const float4*>(SM + O_ACT + kc * 24);
      #pragma unroll
      for (int m = 0; m < 6; ++m) {
        const float4 av = a4[m];
        #pragma unroll
        for (int i = 0; i < 8; ++i) {
          acc[i] = fmaf(av.x, w[i][4*m+0], acc[i]);
          acc[i] = fmaf(av.y, w[i][4*m+1], acc[i]);
          acc[i] = fmaf(av.z, w[i][4*m+2], acc[i]);
          acc[i] = fmaf(av.w, w[i][4*m+3], acc[i]);
        }
      }
    }
    #pragma unroll
    for (int i = 0; i < 8; ++i) acc[i] = sum8(acc[i]);   // octet butterfly (VALU)
    float pre = acc[0];
    #pragma unroll
    for (int i = 1; i < 8; ++i) if (kc == i) pre = acc[i];  // this thread's gate = tid
    pre += bias;
    const bool tg = (tid >= 256) && (tid < 384);            // gg gates -> tanh
    SM[O_RED + tid] = tg ? tanh_f(pre) : sigm(pre);
    __syncthreads();                                        // B1

    // ===== window: cell+publish (w0, prio) | poll (w7) | x (w6) | FC (w2-4) ====
    if (wvid == 0) {
      __builtin_amdgcn_s_setprio(1);       // critical path: publish gates 32 blocks
      const float2 gi  = *reinterpret_cast<const float2*>(SM + O_RED + 2 * lane);
      const float2 gf  = *reinterpret_cast<const float2*>(SM + O_RED + 128 + 2 * lane);
      const float2 gg2 = *reinterpret_cast<const float2*>(SM + O_RED + 256 + 2 * lane);
      const float2 go2 = *reinterpret_cast<const float2*>(SM + O_RED + 384 + 2 * lane);
      cst0 = gf.x * cst0 + gi.x * gg2.x;
      cst1 = gf.y * cst1 + gi.y * gg2.y;
      hc0  = go2.x * tanh_f(cst0);
      hc1  = go2.y * tanh_f(cst1);
      const float sh = wave_sum(tanh_f(hc0) * wt0a + tanh_f(hc1) * wt0b);
      if (lane == 0) {
        SM[O_MISC] = sh;
        if (big) {
          const u64 pv = (((u64)(unsigned)r) << 32) | (u64)__float_as_uint(t5e + sh + EPSF);
          mail_store(&mail[(r & 1) * NB + b], pv);
        }
      }
      __builtin_amdgcn_s_setprio(0);
    } else if (wvid == 7) {
      if (big && lane < NB) {
        u64* slot = &mail[(r & 1) * NB + lane];
        u64 v = mail_load(slot);
        while ((unsigned)(v >> 32) != (unsigned)r) v = mail_load(slot);
        SM[O_DELT + lane] = __uint_as_float((unsigned)v);
      }
    } else if (wvid == 6) {
      if (t + 1 < TST && lane < IDM)
        SM[O_ACT + lane] = myx[(size_t)(t + 1) * IDM + lane];
    } else if (t > 0 && tid >= 128 && tid < 288) {   // waves 2-4: FC for step t-1
      const int cls = (tid - 128) >> 4, p = tid & 15;
      float pt = 0.f;
      #pragma unroll
      for (int i = 0; i < 16; ++i) {
        const int k = p + 16 * i;
        pt = fmaf(SM[O_WFC + cls * 264 + k], SM[O_GEX + k], pt);
      }
      pt = sum16(pt);
      if (p == 0) dout[((size_t)(b * TST + (t - 1))) * NCLS + cls] = pt + SM[O_BFC + cls];
    }
    __syncthreads();                                        // B2

    // ===== scores + own-wave compaction + in-wave distributed gather ===========
    const float s_h = SM[O_MISC];
    float wval = 0.f;
    bool pred = false;
    if (big) {
      if (tid < r) {
        const float sc = s_h + SM[O_SBUF + tid];
        wval = fmaxf(sc - SM[O_DELT + ((b * r + tid) & (NB - 1))], 0.f);
        SM[O_WLDS + tid] = wval;
        pred = (wval > 0.f) && (tid > 0);   // t'=0 row is zeros: no contribution
      }
    } else {
      float scv = (tid < r) ? (s_h + SM[O_SBUF + tid]) : -3e38f;
      float mx = scv;
      mx = fmaxf(mx, __shfl_xor(mx, 1, 64));  mx = fmaxf(mx, __shfl_xor(mx, 2, 64));
      mx = fmaxf(mx, __shfl_xor(mx, 4, 64));  mx = fmaxf(mx, __shfl_xor(mx, 8, 64));
      mx = fmaxf(mx, __shfl_xor(mx, 16, 64)); mx = fmaxf(mx, __shfl_xor(mx, 32, 64));
      if (tid < r) {
        wval = __builtin_amdgcn_exp2f(LOG2E * (scv - mx));
        SM[O_WLDS + tid] = wval;
        pred = (tid > 0);
      }
    }
    const float wsp = wave_sum(wval);        // per-wave denominator partial
    if (lane == 0) SM[O_MISC + 8 + wvid] = wsp;
    const u64 bmask = __ballot((int)pred);
    const int cnt = (int)__popcll(bmask);    // own-wave count, in-register
    if (pred) {                              // pred => tid<r<=384 => wvid<6
      const int pos = (int)__popcll(bmask & ((1ull << lane) - 1ull));
      IDX[(wvid << 6) + pos] = tid;
    }
    // gather: 4 sub-groups x 16 lanes take ranks sub+4k of OWN wave's list;
    // 16 lanes x 8 dims each (distributed-latency pattern, proven R1/R6/R7/R10)
    if (wvid < 6) {
      const int sub = lane >> 4;             // 0..3
      const int j8 = lane & 15;
      float ac0=0.f,ac1=0.f,ac2=0.f,ac3=0.f,ac4=0.f,ac5=0.f,ac6=0.f,ac7=0.f;
      for (int rk = sub; rk < cnt; rk += 4) {
        const int tp = IDX[(wvid << 6) + rk];
        const float wgt = SM[O_WLDS + tp];
        const float* bp = hsout + ((size_t)(b * TST + tp - 1)) * HDM + j8 * 8;
        const float4 v0 = *reinterpret_cast<const float4*>(bp);
        const float4 v1 = *reinterpret_cast<const float4*>(bp + 4);
        ac0 = fmaf(wgt, v0.x, ac0); ac1 = fmaf(wgt, v0.y, ac1);
        ac2 = fmaf(wgt, v0.z, ac2); ac3 = fmaf(wgt, v0.w, ac3);
        ac4 = fmaf(wgt, v1.x, ac4); ac5 = fmaf(wgt, v1.y, ac5);
        ac6 = fmaf(wgt, v1.z, ac6); ac7 = fmaf(wgt, v1.w, ac7);
      }
      ac0 += __shfl_xor(ac0,16,64); ac0 += __shfl_xor(ac0,32,64);
      ac1 += __shfl_xor(ac1,16,64); ac1 += __shfl_xor(ac1,32,64);
      ac2 += __shfl_xor(ac2,16,64); ac2 += __shfl_xor(ac2,32,64);
      ac3 += __shfl_xor(ac3,16,64); ac3 += __shfl_xor(ac3,32,64);
      ac4 += __shfl_xor(ac4,16,64); ac4 += __shfl_xor(ac4,32,64);
      ac5 += __shfl_xor(ac5,16,64); ac5 += __shfl_xor(ac5,32,64);
      ac6 += __shfl_xor(ac6,16,64); ac6 += __shfl_xor(ac6,32,64);
      ac7 += __shfl_xor(ac7,16,64); ac7 += __shfl_xor(ac7,32,64);
      if (sub == 0) {
        float4* r4 = reinterpret_cast<float4*>(SM + O_RED + wvid * 128 + j8 * 8);
        r4[0] = make_float4(ac0, ac1, ac2, ac3);
        r4[1] = make_float4(ac4, ac5, ac6, ac7);
      }
    }
    __syncthreads();                                        // B3

    // ================= finalize (wave 0): h, outputs, s_buf[r], top-5 ==========
    if (wvid == 0) {
      float wsum = 0.f;
      #pragma unroll
      for (int i = 0; i < 8; ++i) wsum += SM[O_MISC + 8 + i];
      const float inv = 1.0f / (wsum + (big ? EPSF : 0.0f));
      float s0 = 0.f, s1 = 0.f;
      #pragma unroll
      for (int wv2 = 0; wv2 < 6; ++wv2) {
        const float2 p2 = reinterpret_cast<const float2*>(SM + O_RED + wv2 * 128)[lane];
        s0 += p2.x; s1 += p2.y;
      }
      const float at0 = s0 * inv, at1 = s1 * inv;
      const float hf0 = hc0 + at0, hf1 = hc1 + at1;
      const float2 hv = make_float2(hf0, hf1);
      reinterpret_cast<float2*>(hsout + (size_t)(b * TST + t) * HDM)[lane] = hv;
      reinterpret_cast<float2*>(SM + O_ACT + 64)[lane] = hv;
      reinterpret_cast<float2*>(SM + O_GEX)[lane] = hv;
      reinterpret_cast<float2*>(SM + O_GEX + 128)[lane] = make_float2(at0, at1);
      if (r < TST) {
        const float tb = wave_sum(tanh_f(hf0) * wt1a + tanh_f(hf1) * wt1b);
        if (lane == 0) SM[O_SBUF + r] = tb;
        if (tb > t5e) {                // uniform insert across wave 0
          if (tb > t5a)      { t5e=t5d; t5d=t5c; t5c=t5b; t5b=t5a; t5a=tb; }
          else if (tb > t5b) { t5e=t5d; t5d=t5c; t5c=t5b; t5b=tb; }
          else if (tb > t5c) { t5e=t5d; t5d=t5c; t5c=tb; }
          else if (tb > t5d) { t5e=t5d; t5d=tb; }
          else               { t5e=tb; }
        }
      }
    }
    __syncthreads();                                        // B4 (loop end)
  }

  // final FC for t = 383 (reads GEX written at last finalize)
  if (tid < 160) {
    const int cls = tid >> 4, p = tid & 15;
    float pt = 0.f;
    #pragma unroll
    for (int i = 0; i < 16; ++i) {
      const int k = p + 16 * i;
      pt = fmaf(SM[O_WFC + cls * 264 + k], SM[O_GEX + k], pt);
    }
    pt = sum16(pt);
    if (p == 0) dout[((size_t)(b * TST + (TST - 1))) * NCLS + cls] = pt + SM[O_BFC + cls];
  }
}

extern "C" void kernel_launch(void* const* d_in, const int* in_sizes, int n_in,
                              void* d_out, int out_size, void* d_ws, size_t ws_size,
                              hipStream_t stream) {
  const float* x   = (const float*)d_in[0];
  const float* Wih = (const float*)d_in[1];
  const float* Whh = (const float*)d_in[2];
  const float* bih = (const float*)d_in[3];
  const float* bhh = (const float*)d_in[4];
  const float* wt  = (const float*)d_in[5];
  const float* Wfc = (const float*)d_in[6];
  const float* bfc = (const float*)d_in[7];
  sab_kernel<<<dim3(NB), dim3(512), 0, stream>>>(
      x, Wih, Whh, bih, bhh, wt, Wfc, bfc, (float*)d_out, (u64*)d_ws);
}